// Round 10
// baseline (762.677 us; speedup 1.0000x reference)
//
#include <hip/hip_runtime.h>
#include <cstdint>
#include <cstddef>

#define S_LEN 512
#define B_DIM 128
#define D_DIM 512
#define T_LEN 64
#define VDEPTH 4
#define OUT_STRIDE ((size_t)B_DIM * D_DIM)
#define CTRL_BYTES ((size_t)B_DIM * S_LEN * 5 * sizeof(float))
#define TRAJ_BYTES ((size_t)B_DIM * S_LEN * T_LEN * sizeof(float))

// ---------------------------------------------------------------------------
// Kernel A: per-row (s,b) controls.
//   ctrl[b][s][0..2] = softmax(values[s,b] @ Wd + bd)
//   ctrl[b][s][3..4] = sigmoid(values[s,b] @ Wrw + brw)
// Layout [B][S][5]: downstream per-b reads are contiguous.
// One wave per row; lane handles k = lane*4 + i*256 (2x float4).
// ---------------------------------------------------------------------------
__global__ __launch_bounds__(256) void namtm_ctrl_kernel(
    const float* __restrict__ values,
    const float* __restrict__ Wd,
    const float* __restrict__ bd,
    const float* __restrict__ Wrw,
    const float* __restrict__ brw,
    float* __restrict__ ctrl)
{
    const int lane = threadIdx.x & 63;
    const int wave = threadIdx.x >> 6;
    const int row  = blockIdx.x * 4 + wave;          // rows = S*B = 65536
    const int s    = row >> 7;                       // row = s*B + b  (B=128)
    const int b    = row & (B_DIM - 1);

    const float* vrow = values + (size_t)row * D_DIM;

    float a0 = 0.f, a1 = 0.f, a2 = 0.f, r0 = 0.f, r1 = 0.f;

#pragma unroll
    for (int i = 0; i < 2; ++i) {
        const int k = lane * 4 + i * 256;
        const float4 q = *reinterpret_cast<const float4*>(vrow + k);
        const float xs[4] = { q.x, q.y, q.z, q.w };
#pragma unroll
        for (int j = 0; j < 4; ++j) {
            const float x = xs[j];
            const int kk = k + j;
            a0 = fmaf(x, Wd[kk * 3 + 0], a0);
            a1 = fmaf(x, Wd[kk * 3 + 1], a1);
            a2 = fmaf(x, Wd[kk * 3 + 2], a2);
            r0 = fmaf(x, Wrw[kk * 2 + 0], r0);
            r1 = fmaf(x, Wrw[kk * 2 + 1], r1);
        }
    }

#pragma unroll
    for (int m = 32; m >= 1; m >>= 1) {
        a0 += __shfl_xor(a0, m, 64);
        a1 += __shfl_xor(a1, m, 64);
        a2 += __shfl_xor(a2, m, 64);
        r0 += __shfl_xor(r0, m, 64);
        r1 += __shfl_xor(r1, m, 64);
    }

    if (lane == 0) {
        a0 += bd[0]; a1 += bd[1]; a2 += bd[2];
        r0 += brw[0]; r1 += brw[1];
        const float mx = fmaxf(a0, fmaxf(a1, a2));
        const float e0 = expf(a0 - mx);
        const float e1 = expf(a1 - mx);
        const float e2 = expf(a2 - mx);
        const float inv = 1.0f / (e0 + e1 + e2);
        float* c = ctrl + ((size_t)b * S_LEN + s) * 5;
        c[0] = e0 * inv;
        c[1] = e1 * inv;
        c[2] = e2 * inv;
        c[3] = 1.0f / (1.0f + expf(-r0));    // read gate  rw[:,0]
        c[4] = 1.0f / (1.0f + expf(-r1));    // write gate rw[:,1]
    }
}

// ---------------------------------------------------------------------------
// pos-trajectory precompute. Grid: B_DIM blocks x 64 lanes.
// traj[b][s][l] = pos at the START of step s (exactly what the scan
// consumes at step s). pos is tape-independent:
//   pos' = roll(pos,-1)*d0 + pos*d1 + roll(pos,1)*d2
//   roll(pos,-1)[l]=pos[l+1] (=pp), roll(pos,1)[l]=pos[l-1] (=pm)
// ~10 us predicted (latency-bound, 128 waves).
// ---------------------------------------------------------------------------
__global__ __launch_bounds__(64) void namtm_pos_traj_kernel(
    const float* __restrict__ ctrl,
    float* __restrict__ traj)
{
    const int lane = threadIdx.x;
    const int b    = blockIdx.x;
    float pos = (lane == 0) ? 1.0f : 0.0f;
    const int lp = (lane + 1) & (T_LEN - 1);
    const int lm = (lane + T_LEN - 1) & (T_LEN - 1);
    const float* cb = ctrl + (size_t)b * S_LEN * 5;
    float* tb = traj + (size_t)b * S_LEN * T_LEN;

#pragma unroll 1
    for (int s = 0; s < S_LEN; ++s) {
        tb[(size_t)s * T_LEN + lane] = pos;
        const float c0 = cb[s * 5 + 0];
        const float c1 = cb[s * 5 + 1];
        const float c2 = cb[s * 5 + 2];
        const float pp = __shfl(pos, lp, 64);
        const float pm = __shfl(pos, lm, 64);
        pos = fmaf(pp, c0, fmaf(pos, c1, pm * c2));
    }
}

// ---------------------------------------------------------------------------
// MAIN tape scan (SMEM p-sourcing, 4-bank deep prefetch):
// p[0..63] for step s comes from the precomputed trajectory, loaded as 16
// float4 VECTOR loads (uniformity defeated via an opaque-zero VGPR index so
// the compiler cannot scalarize into s_load -> SGPR-budget blowout).
// Loads are issued THREE steps ahead through a 4-bank register rotation
// (~840 cyc coverage vs ~500-900 cyc L3/HBM fill; all 4 waves share the
// fill so TLP can't hide it -- depth must).
// Hot loop: 128 fma + ~10 misc ~= 280 cyc/step/SIMD -> ~60-70 us predicted.
// No readlane, no shfl, no LDS traffic, no barriers in the loop.
// Grid: 256 blocks x 256 threads = 1 wave/SIMD (VGPR budget up to 512 free;
// est ~350 used: tape 64 + banks 256 + misc).
// ---------------------------------------------------------------------------
__global__ __launch_bounds__(256, 1) void namtm_tape_smem_kernel(
    const float* __restrict__ values,
    const float* __restrict__ ctrl,
    const float* __restrict__ traj,
    float* __restrict__ out)
{
    __shared__ __align__(16) float ctrlL[S_LEN][8];     // 16 KB, b128-aligned rows

    const int tid = threadIdx.x;
    const int b   = blockIdx.x >> 1;
    const int d   = ((blockIdx.x & 1) << 8) + tid;

    // Stage this b's controls: contiguous coalesced read of 2560 floats.
    {
        const float* csrc = ctrl + (size_t)b * S_LEN * 5;
        for (int e = tid; e < S_LEN * 5; e += 256) {
            const int s = e / 5;
            const int j = e - s * 5;
            ctrlL[s][j] = csrc[e];
        }
    }
    __syncthreads();   // once, before the loop

    float tape[T_LEN];
#pragma unroll
    for (int l = 0; l < T_LEN; ++l) tape[l] = 0.0f;

    // Opaque zero in a VGPR: makes the traj address formally non-uniform so
    // the backend emits global_load_dwordx4 (VGPR dest, auto s_waitcnt)
    // instead of s_load (SGPR dest -- 4 banks x 64 f32 would need 256 SGPRs
    // against a ~102 budget and wreck the schedule).
    int vz = 0;
    asm volatile("" : "+v"(vz));
    const float* tbv   = traj + (size_t)b * S_LEN * T_LEN + vz;
    const float* vbase = values + (size_t)b * D_DIM + d;
    float* outp        = out + (size_t)b * D_DIM + d;

    // prologue: p(0), p(1), p(2) into banks A, B, C (D filled at s=0)
    float4 pA[16], pB[16], pC[16], pD[16];
#pragma unroll
    for (int i = 0; i < 16; ++i) {
        pA[i] = *reinterpret_cast<const float4*>(tbv + 0 * T_LEN + i * 4);
        pB[i] = *reinterpret_cast<const float4*>(tbv + 1 * T_LEN + i * 4);
        pC[i] = *reinterpret_cast<const float4*>(tbv + 2 * T_LEN + i * 4);
    }

    // 4-deep values prefetch (covers ~900cy fill at ~280cy/step)
    float v0 = vbase[(size_t)0 << 16];
    float v1 = vbase[(size_t)1 << 16];
    float v2 = vbase[(size_t)2 << 16];
    float v3 = vbase[(size_t)3 << 16];

    // Rotation: step s consumes bank[s&3], fills bank[(s+3)&3] (freed at
    // s-1) with p(s+3). Tail clamp only rewrites never-again-consumed banks.
#define SSTEP(S_, PC, PL)                                                     \
    do {                                                                      \
        const int s_ = (S_);                                                  \
        /* issue p(s+3) into freed bank PL (3-step-ahead vector loads) */     \
        { const int sn_ = (s_ + 3 < S_LEN) ? (s_ + 3) : (S_LEN - 1);          \
          const float* pt_ = tbv + (size_t)sn_ * T_LEN;                       \
          _Pragma("unroll")                                                   \
          for (int i = 0; i < 16; ++i)                                        \
              PL[i] = *reinterpret_cast<const float4*>(pt_ + i * 4); }        \
        const float4 cq = *reinterpret_cast<const float4*>(&ctrlL[s_][0]);    \
        const float c4_ = ctrlL[s_][4];                                       \
        /* values fifo */                                                     \
        const float v_ = v0; v0 = v1; v1 = v2; v2 = v3;                       \
        { const int sl_ = (s_ + VDEPTH < S_LEN) ? (s_ + VDEPTH) : (S_LEN - 1);\
          v3 = vbase[(size_t)sl_ << 16]; }                                    \
        /* oldval = sum_l p[l]*tape[l] (PC bank loaded 3 steps ago) */        \
        float a0_ = 0.f, a1_ = 0.f, a2_ = 0.f, a3_ = 0.f;                     \
        _Pragma("unroll")                                                     \
        for (int i = 0; i < 16; ++i) {                                        \
            a0_ = fmaf(PC[i].x, tape[4 * i + 0], a0_);                        \
            a1_ = fmaf(PC[i].y, tape[4 * i + 1], a1_);                        \
            a2_ = fmaf(PC[i].z, tape[4 * i + 2], a2_);                        \
            a3_ = fmaf(PC[i].w, tape[4 * i + 3], a3_);                        \
        }                                                                     \
        const float old_ = (a0_ + a1_) + (a2_ + a3_);                         \
        outp[(size_t)s_ * OUT_STRIDE] = old_ * cq.w;  /* cq.w = read gate */  \
        const float w_ = (v_ - old_) * c4_;           /* c4_ = write gate */  \
        _Pragma("unroll")                                                     \
        for (int i = 0; i < 16; ++i) {                                        \
            tape[4 * i + 0] = fmaf(PC[i].x, w_, tape[4 * i + 0]);             \
            tape[4 * i + 1] = fmaf(PC[i].y, w_, tape[4 * i + 1]);             \
            tape[4 * i + 2] = fmaf(PC[i].z, w_, tape[4 * i + 2]);             \
            tape[4 * i + 3] = fmaf(PC[i].w, w_, tape[4 * i + 3]);             \
        }                                                                     \
    } while (0)

#pragma unroll 1
    for (int s = 0; s < S_LEN; s += 4) {
        SSTEP(s,     pA, pD);
        SSTEP(s + 1, pB, pA);
        SSTEP(s + 2, pC, pB);
        SSTEP(s + 3, pD, pC);
    }
#undef SSTEP

    // Final tape write-out: out[S*B*D + ((l*B + b)*D + d)]
    const size_t tape_off = (size_t)S_LEN * B_DIM * D_DIM;
#pragma unroll
    for (int l = 0; l < T_LEN; ++l) {
        out[tape_off + ((size_t)l * B_DIM + b) * D_DIM + d] = tape[l];
    }
}

// ---------------------------------------------------------------------------
// FALLBACK tape scan (readlane p-distribution) — hand-verified round-6
// kernel, unchanged. 64 readlane + 128 fma ~= 384 cyc/step -> ~85 us.
// MODE 0: ctrl staged from d_ws. MODE 1: ctrl recomputed block-locally
// (no workspace; no inter-block ordering assumptions).
// ---------------------------------------------------------------------------
template <int MODE>
__global__ __launch_bounds__(256, 1) void namtm_tape_kernel(
    const float* __restrict__ values,
    const float* __restrict__ ctrl,
    const float* __restrict__ Wd,
    const float* __restrict__ bd,
    const float* __restrict__ Wrw,
    const float* __restrict__ brw,
    float* __restrict__ out)
{
    __shared__ __align__(16) float ctrlL[S_LEN][8];

    const int tid  = threadIdx.x;
    const int lane = tid & 63;
    const int b    = blockIdx.x >> 1;
    const int d    = ((blockIdx.x & 1) << 8) + tid;

    if (MODE == 0) {
        const float* csrc = ctrl + (size_t)b * S_LEN * 5;
        for (int e = tid; e < S_LEN * 5; e += 256) {
            const int s = e / 5;
            const int j = e - s * 5;
            ctrlL[s][j] = csrc[e];
        }
    } else {
#pragma unroll
        for (int rep = 0; rep < 2; ++rep) {
            const int s = tid + rep * 256;
            const float* vrow = values + ((size_t)s * B_DIM + b) * D_DIM;
            float a0 = 0.f, a1 = 0.f, a2 = 0.f, r0 = 0.f, r1 = 0.f;
            for (int k = 0; k < D_DIM; k += 4) {
                const float4 q = *reinterpret_cast<const float4*>(vrow + k);
                const float xs[4] = { q.x, q.y, q.z, q.w };
#pragma unroll
                for (int j = 0; j < 4; ++j) {
                    const float x = xs[j];
                    const int kk = k + j;
                    a0 = fmaf(x, Wd[kk * 3 + 0], a0);
                    a1 = fmaf(x, Wd[kk * 3 + 1], a1);
                    a2 = fmaf(x, Wd[kk * 3 + 2], a2);
                    r0 = fmaf(x, Wrw[kk * 2 + 0], r0);
                    r1 = fmaf(x, Wrw[kk * 2 + 1], r1);
                }
            }
            a0 += bd[0]; a1 += bd[1]; a2 += bd[2];
            r0 += brw[0]; r1 += brw[1];
            const float mx = fmaxf(a0, fmaxf(a1, a2));
            const float e0 = expf(a0 - mx);
            const float e1 = expf(a1 - mx);
            const float e2 = expf(a2 - mx);
            const float inv = 1.0f / (e0 + e1 + e2);
            ctrlL[s][0] = e0 * inv;
            ctrlL[s][1] = e1 * inv;
            ctrlL[s][2] = e2 * inv;
            ctrlL[s][3] = 1.0f / (1.0f + expf(-r0));
            ctrlL[s][4] = 1.0f / (1.0f + expf(-r1));
        }
    }
    __syncthreads();

    float tape[T_LEN];
#pragma unroll
    for (int l = 0; l < T_LEN; ++l) tape[l] = 0.0f;

    float pos = (lane == 0) ? 1.0f : 0.0f;
    const int lp = (lane + 1) & (T_LEN - 1);
    const int lm = (lane + T_LEN - 1) & (T_LEN - 1);

    const float* vbase = values + (size_t)b * D_DIM + d;
    float* outp = out + (size_t)b * D_DIM + d;

    float v0 = vbase[(size_t)0 << 16];
    float v1 = vbase[(size_t)1 << 16];
    float v2 = vbase[(size_t)2 << 16];
    float v3 = vbase[(size_t)3 << 16];

#pragma unroll 1
    for (int s = 0; s < S_LEN; ++s) {
        const float4 cq = *reinterpret_cast<const float4*>(&ctrlL[s][0]);
        const float c4_ = ctrlL[s][4];

        const float pp_ = __shfl(pos, lp, 64);
        const float pm_ = __shfl(pos, lm, 64);

        const int pbits = __float_as_int(pos);
        int pi[T_LEN];
#pragma unroll
        for (int l = 0; l < T_LEN; ++l)
            pi[l] = __builtin_amdgcn_readlane(pbits, l);

        const float v_ = v0; v0 = v1; v1 = v2; v2 = v3;
        {
            const int sl_ = (s + VDEPTH < S_LEN) ? (s + VDEPTH) : (S_LEN - 1);
            v3 = vbase[(size_t)sl_ << 16];
        }

        float a0_ = 0.f, a1_ = 0.f, a2_ = 0.f, a3_ = 0.f;
#pragma unroll
        for (int l = 0; l < T_LEN; l += 4) {
            a0_ = fmaf(__int_as_float(pi[l + 0]), tape[l + 0], a0_);
            a1_ = fmaf(__int_as_float(pi[l + 1]), tape[l + 1], a1_);
            a2_ = fmaf(__int_as_float(pi[l + 2]), tape[l + 2], a2_);
            a3_ = fmaf(__int_as_float(pi[l + 3]), tape[l + 3], a3_);
        }
        const float old_ = (a0_ + a1_) + (a2_ + a3_);

        outp[(size_t)s * OUT_STRIDE] = old_ * cq.w;

        const float w_ = (v_ - old_) * c4_;
#pragma unroll
        for (int l = 0; l < T_LEN; ++l)
            tape[l] = fmaf(__int_as_float(pi[l]), w_, tape[l]);

        pos = fmaf(pp_, cq.x, fmaf(pos, cq.y, pm_ * cq.z));
    }

    const size_t tape_off = (size_t)S_LEN * B_DIM * D_DIM;
#pragma unroll
    for (int l = 0; l < T_LEN; ++l) {
        out[tape_off + ((size_t)l * B_DIM + b) * D_DIM + d] = tape[l];
    }
}

// ---------------------------------------------------------------------------
extern "C" void kernel_launch(void* const* d_in, const int* in_sizes, int n_in,
                              void* d_out, int out_size, void* d_ws, size_t ws_size,
                              hipStream_t stream)
{
    const float* values = (const float*)d_in[0];   // [S, B, D]
    const float* Wd     = (const float*)d_in[1];   // [D, 3]
    const float* bd     = (const float*)d_in[2];   // [3]
    const float* Wrw    = (const float*)d_in[3];   // [D, 2]
    const float* brw    = (const float*)d_in[4];   // [2]
    float* out = (float*)d_out;                    // reads [S,B,D] ++ tape [T,B,D]

    // ws layout: [ctrl 1.31MB][traj 16.78MB]. ws_size is constant across
    // calls -> host-side branches are graph-capture-safe.
    if (ws_size >= CTRL_BYTES + TRAJ_BYTES) {
        float* ctrl = (float*)d_ws;
        float* traj = (float*)((char*)d_ws + CTRL_BYTES);
        hipLaunchKernelGGL(namtm_ctrl_kernel,
                           dim3((S_LEN * B_DIM) / 4), dim3(256), 0, stream,
                           values, Wd, bd, Wrw, brw, ctrl);
        hipLaunchKernelGGL(namtm_pos_traj_kernel,
                           dim3(B_DIM), dim3(64), 0, stream, ctrl, traj);
        hipLaunchKernelGGL(namtm_tape_smem_kernel,
                           dim3(B_DIM * 2), dim3(256), 0, stream,
                           values, ctrl, traj, out);
    } else if (ws_size >= CTRL_BYTES) {
        float* ctrl = (float*)d_ws;
        hipLaunchKernelGGL(namtm_ctrl_kernel,
                           dim3((S_LEN * B_DIM) / 4), dim3(256), 0, stream,
                           values, Wd, bd, Wrw, brw, ctrl);
        hipLaunchKernelGGL((namtm_tape_kernel<0>),
                           dim3(B_DIM * 2), dim3(256), 0, stream,
                           values, ctrl, Wd, bd, Wrw, brw, out);
    } else {
        hipLaunchKernelGGL((namtm_tape_kernel<1>),
                           dim3(B_DIM * 2), dim3(256), 0, stream,
                           values, (const float*)nullptr, Wd, bd, Wrw, brw, out);
    }
}

// Round 11
// 582.270 us; speedup vs baseline: 1.3098x; 1.3098x over previous
//
#include <hip/hip_runtime.h>
#include <cstdint>
#include <cstddef>

#define S_LEN 512
#define B_DIM 128
#define D_DIM 512
#define T_LEN 64
#define VDEPTH 4
#define OUT_STRIDE ((size_t)B_DIM * D_DIM)
#define CTRL_BYTES ((size_t)B_DIM * S_LEN * 5 * sizeof(float))

// ---------------------------------------------------------------------------
// Kernel A: per-row (s,b) controls.
//   ctrl[b][s][0..2] = softmax(values[s,b] @ Wd + bd)
//   ctrl[b][s][3..4] = sigmoid(values[s,b] @ Wrw + brw)
// Layout [B][S][5]: downstream per-b reads are contiguous.
// One wave per row; lane handles k = lane*4 + i*256 (2x float4).
// ~25-35 us, memory-bound (reads values once, 134 MB).
// ---------------------------------------------------------------------------
__global__ __launch_bounds__(256) void namtm_ctrl_kernel(
    const float* __restrict__ values,
    const float* __restrict__ Wd,
    const float* __restrict__ bd,
    const float* __restrict__ Wrw,
    const float* __restrict__ brw,
    float* __restrict__ ctrl)
{
    const int lane = threadIdx.x & 63;
    const int wave = threadIdx.x >> 6;
    const int row  = blockIdx.x * 4 + wave;          // rows = S*B = 65536
    const int s    = row >> 7;                       // row = s*B + b  (B=128)
    const int b    = row & (B_DIM - 1);

    const float* vrow = values + (size_t)row * D_DIM;

    float a0 = 0.f, a1 = 0.f, a2 = 0.f, r0 = 0.f, r1 = 0.f;

#pragma unroll
    for (int i = 0; i < 2; ++i) {
        const int k = lane * 4 + i * 256;
        const float4 q = *reinterpret_cast<const float4*>(vrow + k);
        const float xs[4] = { q.x, q.y, q.z, q.w };
#pragma unroll
        for (int j = 0; j < 4; ++j) {
            const float x = xs[j];
            const int kk = k + j;
            a0 = fmaf(x, Wd[kk * 3 + 0], a0);
            a1 = fmaf(x, Wd[kk * 3 + 1], a1);
            a2 = fmaf(x, Wd[kk * 3 + 2], a2);
            r0 = fmaf(x, Wrw[kk * 2 + 0], r0);
            r1 = fmaf(x, Wrw[kk * 2 + 1], r1);
        }
    }

#pragma unroll
    for (int m = 32; m >= 1; m >>= 1) {
        a0 += __shfl_xor(a0, m, 64);
        a1 += __shfl_xor(a1, m, 64);
        a2 += __shfl_xor(a2, m, 64);
        r0 += __shfl_xor(r0, m, 64);
        r1 += __shfl_xor(r1, m, 64);
    }

    if (lane == 0) {
        a0 += bd[0]; a1 += bd[1]; a2 += bd[2];
        r0 += brw[0]; r1 += brw[1];
        const float mx = fmaxf(a0, fmaxf(a1, a2));
        const float e0 = expf(a0 - mx);
        const float e1 = expf(a1 - mx);
        const float e2 = expf(a2 - mx);
        const float inv = 1.0f / (e0 + e1 + e2);
        float* c = ctrl + ((size_t)b * S_LEN + s) * 5;
        c[0] = e0 * inv;
        c[1] = e1 * inv;
        c[2] = e2 * inv;
        c[3] = 1.0f / (1.0f + expf(-r0));    // read gate  rw[:,0]
        c[4] = 1.0f / (1.0f + expf(-r1));    // write gate rw[:,1]
    }
}

// ---------------------------------------------------------------------------
// MAIN tape scan — READLANE p-distribution (promoted after r10 post-mortem).
//
// r10 evidence: the global-memory p-prefetch variant measured 492 us,
// VALUBusy 45%, VGPR 216 (< the 320 the 4-bank pipeline needs) -> the
// compiler collapsed the prefetch and serialized on wave-global vmcnt:
// every step drained a cold-HBM values load (~900 cyc). Latency-bound.
//
// This variant keeps p in SGPRs via 64 v_readlane: p distribution costs
// VALU issue only (no memory ops, no in-flight pressure, nothing the
// compiler can de-pipeline). Loop VMEM = 4-deep values FIFO (4 loads in
// flight, the simple pattern the compiler's counted-vmcnt handles) +
// 1 coalesced store.
// Model: 64 readlane (128c) + 128 fma (256c) + ~55c misc ~= 440 cyc/step
// -> ~94 us. Grid: 256 blocks x 256 threads (1 wave/SIMD, grid-forced);
// thread owns (b, d); tape[64] in VGPRs; pos carried per-wave in a
// register (2 shfl + 3 fma). NO barriers in the loop.
// MODE 0: ctrl staged from d_ws. MODE 1: ctrl recomputed block-locally.
// ---------------------------------------------------------------------------
template <int MODE>
__global__ __launch_bounds__(256, 1) void namtm_tape_kernel(
    const float* __restrict__ values,
    const float* __restrict__ ctrl,
    const float* __restrict__ Wd,
    const float* __restrict__ bd,
    const float* __restrict__ Wrw,
    const float* __restrict__ brw,
    float* __restrict__ out)
{
    __shared__ __align__(16) float ctrlL[S_LEN][8];     // 16 KB, b128-aligned rows

    const int tid  = threadIdx.x;
    const int lane = tid & 63;
    const int b    = blockIdx.x >> 1;
    const int d    = ((blockIdx.x & 1) << 8) + tid;

    if (MODE == 0) {
        // Stage this b's controls: contiguous coalesced read of 2560 floats.
        const float* csrc = ctrl + (size_t)b * S_LEN * 5;
        for (int e = tid; e < S_LEN * 5; e += 256) {
            const int s = e / 5;
            const int j = e - s * 5;
            ctrlL[s][j] = csrc[e];
        }
    } else {
        // Recompute this b's controls in-block (no workspace dependency).
#pragma unroll
        for (int rep = 0; rep < 2; ++rep) {
            const int s = tid + rep * 256;
            const float* vrow = values + ((size_t)s * B_DIM + b) * D_DIM;
            float a0 = 0.f, a1 = 0.f, a2 = 0.f, r0 = 0.f, r1 = 0.f;
            for (int k = 0; k < D_DIM; k += 4) {
                const float4 q = *reinterpret_cast<const float4*>(vrow + k);
                const float xs[4] = { q.x, q.y, q.z, q.w };
#pragma unroll
                for (int j = 0; j < 4; ++j) {
                    const float x = xs[j];
                    const int kk = k + j;
                    a0 = fmaf(x, Wd[kk * 3 + 0], a0);
                    a1 = fmaf(x, Wd[kk * 3 + 1], a1);
                    a2 = fmaf(x, Wd[kk * 3 + 2], a2);
                    r0 = fmaf(x, Wrw[kk * 2 + 0], r0);
                    r1 = fmaf(x, Wrw[kk * 2 + 1], r1);
                }
            }
            a0 += bd[0]; a1 += bd[1]; a2 += bd[2];
            r0 += brw[0]; r1 += brw[1];
            const float mx = fmaxf(a0, fmaxf(a1, a2));
            const float e0 = expf(a0 - mx);
            const float e1 = expf(a1 - mx);
            const float e2 = expf(a2 - mx);
            const float inv = 1.0f / (e0 + e1 + e2);
            ctrlL[s][0] = e0 * inv;
            ctrlL[s][1] = e1 * inv;
            ctrlL[s][2] = e2 * inv;
            ctrlL[s][3] = 1.0f / (1.0f + expf(-r0));
            ctrlL[s][4] = 1.0f / (1.0f + expf(-r1));
        }
    }
    __syncthreads();   // once, before the loop

    float tape[T_LEN];
#pragma unroll
    for (int l = 0; l < T_LEN; ++l) tape[l] = 0.0f;

    float pos = (lane == 0) ? 1.0f : 0.0f;
    const int lp = (lane + 1) & (T_LEN - 1);           // src lane for pos[lane+1]
    const int lm = (lane + T_LEN - 1) & (T_LEN - 1);   // src lane for pos[lane-1]

    const float* vbase = values + (size_t)b * D_DIM + d;
    float* outp = out + (size_t)b * D_DIM + d;

    // 4-deep values FIFO (covers ~900cy cold-HBM miss at ~440cy/step)
    float v0 = vbase[(size_t)0 << 16];
    float v1 = vbase[(size_t)1 << 16];
    float v2 = vbase[(size_t)2 << 16];
    float v3 = vbase[(size_t)3 << 16];

#pragma unroll 1
    for (int s = 0; s < S_LEN; ++s) {
        const float4 cq = *reinterpret_cast<const float4*>(&ctrlL[s][0]);
        const float c4_ = ctrlL[s][4];

        // ref: pos' = roll(pos,-1)*d0 + pos*d1 + roll(pos,1)*d2
        //      roll(pos,-1)[l]=pos[l+1]=pp_, roll(pos,1)[l]=pos[l-1]=pm_
        const float pp_ = __shfl(pos, lp, 64);
        const float pm_ = __shfl(pos, lm, 64);

        // p[0..63] -> SGPRs via readlane; read once, reused by the dot
        // and the rank-1 update. VALU-only: no memory, no vmcnt coupling.
        const int pbits = __float_as_int(pos);
        int pi[T_LEN];
#pragma unroll
        for (int l = 0; l < T_LEN; ++l)
            pi[l] = __builtin_amdgcn_readlane(pbits, l);

        // values fifo
        const float v_ = v0; v0 = v1; v1 = v2; v2 = v3;
        {
            const int sl_ = (s + VDEPTH < S_LEN) ? (s + VDEPTH) : (S_LEN - 1);
            v3 = vbase[(size_t)sl_ << 16];
        }

        // oldval = sum_l p[l]*tape[l]  (4 independent accumulator chains)
        float a0_ = 0.f, a1_ = 0.f, a2_ = 0.f, a3_ = 0.f;
#pragma unroll
        for (int l = 0; l < T_LEN; l += 4) {
            a0_ = fmaf(__int_as_float(pi[l + 0]), tape[l + 0], a0_);
            a1_ = fmaf(__int_as_float(pi[l + 1]), tape[l + 1], a1_);
            a2_ = fmaf(__int_as_float(pi[l + 2]), tape[l + 2], a2_);
            a3_ = fmaf(__int_as_float(pi[l + 3]), tape[l + 3], a3_);
        }
        const float old_ = (a0_ + a1_) + (a2_ + a3_);

        outp[(size_t)s * OUT_STRIDE] = old_ * cq.w;   // cq.w = read gate

        const float w_ = (v_ - old_) * c4_;           // c4_ = write gate
#pragma unroll
        for (int l = 0; l < T_LEN; ++l)
            tape[l] = fmaf(__int_as_float(pi[l]), w_, tape[l]);

        pos = fmaf(pp_, cq.x, fmaf(pos, cq.y, pm_ * cq.z));
    }

    // Final tape write-out: out[S*B*D + ((l*B + b)*D + d)]
    const size_t tape_off = (size_t)S_LEN * B_DIM * D_DIM;
#pragma unroll
    for (int l = 0; l < T_LEN; ++l) {
        out[tape_off + ((size_t)l * B_DIM + b) * D_DIM + d] = tape[l];
    }
}

// ---------------------------------------------------------------------------
extern "C" void kernel_launch(void* const* d_in, const int* in_sizes, int n_in,
                              void* d_out, int out_size, void* d_ws, size_t ws_size,
                              hipStream_t stream)
{
    const float* values = (const float*)d_in[0];   // [S, B, D]
    const float* Wd     = (const float*)d_in[1];   // [D, 3]
    const float* bd     = (const float*)d_in[2];   // [3]
    const float* Wrw    = (const float*)d_in[3];   // [D, 2]
    const float* brw    = (const float*)d_in[4];   // [2]
    float* out = (float*)d_out;                    // reads [S,B,D] ++ tape [T,B,D]

    // ws_size is constant across calls -> host-side branch is graph-safe.
    // (r10 measured ws_size >= 18 MB, so MODE 0 is the live path.)
    if (ws_size >= CTRL_BYTES) {
        float* ctrl = (float*)d_ws;                // [B][S][5], 1.31 MB
        hipLaunchKernelGGL(namtm_ctrl_kernel,
                           dim3((S_LEN * B_DIM) / 4), dim3(256), 0, stream,
                           values, Wd, bd, Wrw, brw, ctrl);
        hipLaunchKernelGGL((namtm_tape_kernel<0>),
                           dim3(B_DIM * 2), dim3(256), 0, stream,
                           values, ctrl, Wd, bd, Wrw, brw, out);
    } else {
        hipLaunchKernelGGL((namtm_tape_kernel<1>),
                           dim3(B_DIM * 2), dim3(256), 0, stream,
                           values, (const float*)nullptr, Wd, bd, Wrw, brw, out);
    }
}